// Round 16
// baseline (2039.681 us; speedup 1.0000x reference)
//
#include <hip/hip_runtime.h>

// Gemma3 forward, MI355X. Round 16: r15 champion + deeper split-K on the
// smallest grids: wo 2->4 slices (160 blocks), wd 4->8 slices (320 blocks).
// L=18 H=640 NH=4 NKV=1 HD=256 I=2048 V=32768 B=1 S=1024 WINDOW=512

typedef unsigned short u16;
typedef __attribute__((ext_vector_type(4))) float f32x4;
typedef __attribute__((ext_vector_type(8))) short bf16x8;

#define DEV static __device__ __forceinline__

DEV u16 f2bf(float f) {  // round-to-nearest-even fp32 -> bf16
  union { float f; unsigned u; } x; x.f = f;
  unsigned r = x.u + 0x7fffu + ((x.u >> 16) & 1u);
  return (u16)(r >> 16);
}

#define GLOAD16(gp, lp) __builtin_amdgcn_global_load_lds( \
    (const __attribute__((address_space(1))) void*)(gp), \
    (__attribute__((address_space(3))) void*)(lp), 16, 0, 0)

DEV float blockSum(float v, float* red) {
#pragma unroll
  for (int o = 32; o; o >>= 1) v += __shfl_down(v, o);
  int lane = threadIdx.x & 63, wid = threadIdx.x >> 6;
  if (lane == 0) red[wid] = v;
  __syncthreads();
  float s = red[0] + red[1] + red[2] + red[3];
  __syncthreads();
  return s;
}

DEV float blockMax(float v, float* red) {
#pragma unroll
  for (int o = 32; o; o >>= 1) v = fmaxf(v, __shfl_down(v, o));
  int lane = threadIdx.x & 63, wid = threadIdx.x >> 6;
  if (lane == 0) red[wid] = v;
  __syncthreads();
  float s = fmaxf(fmaxf(red[0], red[1]), fmaxf(red[2], red[3]));
  __syncthreads();
  return s;
}

DEV void cstore(float* C, size_t i, float v) { C[i] = v; }
DEV void cstore(u16* C, size_t i, float v) { C[i] = f2bf(v); }

// ---- GEMM NT: C[M,N] = alpha * A[M,K]bf16 * (B[N,K]bf16)^T ----
// 128x128 tile. BKT=64: swizzle key row&7 (proven). BKT=32: 32KB LDS,
// swizzle key (row>>1)&3 (conflict-free, proven r13/r14). Double-buffered
// LDS, depth-1 prefetch via global_load_lds, pre-swizzled source column.
// nshift: -1 plain; -2 causal tile-skip; >=0 sliding band n0=m0-nshift+bx*128.
// kmode: 0 full K; 1 sliding K-band; 2 causal K-band; 3 split-K over blockIdx.z.
// GEGLU=1: B rows g/u-interleaved at 16-col granularity.
template <typename CT, int GEGLU, int BKT>
__global__ __launch_bounds__(256) void gemm_nt(
    const u16* __restrict__ A, int lda, long sA,
    const u16* __restrict__ B, int ldb, long sB,
    CT* __restrict__ C, int ldc, long sC,
    int K, float alpha, int kmode, int nshift, int ksplit) {
  constexpr int DB = 128 * BKT;             // elems per LDS buffer
  __shared__ __align__(16) u16 As[2 * DB];
  __shared__ __align__(16) u16 Bs[2 * DB];
  const int m0 = blockIdx.y * 128;
  int n0;
  if (nshift == -1) n0 = blockIdx.x * 128;
  else if (nshift == -2) { n0 = blockIdx.x * 128; if (n0 > m0) return; }
  else { n0 = m0 - nshift + blockIdx.x * 128; if (n0 < 0) return; }
  int klo = 0, khi = K;
  if (kmode == 1) { klo = m0 - 512; if (klo < 0) klo = 0; khi = m0 + 128; if (khi > K) khi = K; }
  else if (kmode == 2) { khi = m0 + 128; if (khi > K) khi = K; }
  else if (kmode == 3) { int kl = K / ksplit; klo = blockIdx.z * kl; khi = klo + kl; }
  A += (long)blockIdx.z * sA;
  B += (long)blockIdx.z * sB;

  const int t = threadIdx.x;
  const int l = t & 63, w = t >> 6;
  const int wr = w >> 1, wc = w & 1;        // 2x2 waves, each 64x64 out
  const int lr = l & 15, lk = l >> 4;
  const int srow = (BKT == 64) ? (t >> 3) : (t >> 2);
  const int scolx = (BKT == 64) ? (((t & 7) ^ (srow & 7)) << 3)
                                : (((t & 3) ^ ((srow >> 1) & 3)) << 3);
  const u16* Ag = A + (size_t)(m0 + srow) * lda + scolx;
  const u16* Bg = B + (size_t)(n0 + srow) * ldb + scolx;
  const int nsteps = (khi - klo) / BKT;

  auto stage = [&](int db, int k0) {
    u16* al = As + db * DB + w * 512;       // wave-uniform LDS bases
    u16* bl = Bs + db * DB + w * 512;
    if constexpr (BKT == 64) {
#pragma unroll
      for (int p = 0; p < 4; ++p) {         // rows p*32 + srow(0..31)
        GLOAD16(Ag + k0 + (size_t)(32 * p) * lda, al + p * 2048);
        GLOAD16(Bg + k0 + (size_t)(32 * p) * ldb, bl + p * 2048);
      }
    } else {
#pragma unroll
      for (int p = 0; p < 2; ++p) {         // rows p*64 + srow(0..63)
        GLOAD16(Ag + k0 + (size_t)(64 * p) * lda, al + p * 2048);
        GLOAD16(Bg + k0 + (size_t)(64 * p) * ldb, bl + p * 2048);
      }
    }
  };

  stage(0, klo);
  f32x4 acc[4][4] = {};

  for (int s = 0; s < nsteps; ++s) {
    __syncthreads();                        // drains prefetch; joins prior ds_reads
    const int db = s & 1;
    if (s + 1 < nsteps) stage(db ^ 1, klo + (s + 1) * BKT);
    const u16* Ab = As + db * DB;
    const u16* Bb = Bs + db * DB;
    if constexpr (BKT == 64) {
      const int axr = lr & 7;
      bf16x8 af[2][4], bfr[2][4];
#pragma unroll
      for (int kk = 0; kk < 2; ++kk)
#pragma unroll
        for (int i = 0; i < 4; ++i) {
          af[kk][i]  = *(const bf16x8*)&Ab[(wr * 64 + i * 16 + lr) * 64 + (((kk * 4 + lk) ^ axr) << 3)];
          bfr[kk][i] = *(const bf16x8*)&Bb[(wc * 64 + i * 16 + lr) * 64 + (((kk * 4 + lk) ^ axr) << 3)];
        }
#pragma unroll
      for (int kk = 0; kk < 2; ++kk)
#pragma unroll
        for (int mi = 0; mi < 4; ++mi)
#pragma unroll
          for (int ni = 0; ni < 4; ++ni)
            acc[mi][ni] = __builtin_amdgcn_mfma_f32_16x16x32_bf16(af[kk][mi], bfr[kk][ni], acc[mi][ni], 0, 0, 0);
    } else {
      const int key = (lr >> 1) & 3;        // (row>>1)&3; i*16 offsets drop out
      bf16x8 af[4], bfr[4];
#pragma unroll
      for (int i = 0; i < 4; ++i) {
        af[i]  = *(const bf16x8*)&Ab[(wr * 64 + i * 16 + lr) * 32 + ((lk ^ key) << 3)];
        bfr[i] = *(const bf16x8*)&Bb[(wc * 64 + i * 16 + lr) * 32 + ((lk ^ key) << 3)];
      }
#pragma unroll
      for (int mi = 0; mi < 4; ++mi)
#pragma unroll
        for (int ni = 0; ni < 4; ++ni)
          acc[mi][ni] = __builtin_amdgcn_mfma_f32_16x16x32_bf16(af[mi], bfr[ni], acc[mi][ni], 0, 0, 0);
    }
  }

  C += (long)blockIdx.z * sC;
  if (GEGLU) {
    // acc[ni]: B rows n0+wc*64+ni*16+lr; rows (r&31)<16 are g, >=16 are u.
#pragma unroll
    for (int mi = 0; mi < 4; ++mi) {
      int row = m0 + wr * 64 + mi * 16 + lk * 4;
#pragma unroll
      for (int np = 0; np < 2; ++np) {
        int col = (n0 + wc * 64) / 2 + np * 16 + lr;
#pragma unroll
        for (int j = 0; j < 4; ++j) {
          float g = acc[mi][2 * np][j], u = acc[mi][2 * np + 1][j];
          float z = 0.7978845608028654f * (g + 0.044715f * g * g * g);
          float th = 2.0f / (1.0f + __expf(-2.0f * z)) - 1.0f;
          cstore(C, (size_t)(row + j) * ldc + col, 0.5f * g * (1.0f + th) * u);
        }
      }
    }
  } else {
#pragma unroll
    for (int mi = 0; mi < 4; ++mi) {
      int row = m0 + wr * 64 + mi * 16 + lk * 4;
#pragma unroll
      for (int ni = 0; ni < 4; ++ni) {
        int col = n0 + wc * 64 + ni * 16 + lr;
#pragma unroll
        for (int j = 0; j < 4; ++j)
          cstore(C, (size_t)(row + j) * ldc + col, acc[mi][ni][j] * alpha);
      }
    }
  }
}

// ---- small kernels ----
__global__ void conv_bf16_kernel(const float* __restrict__ in, u16* __restrict__ out, long n4) {
  for (long i = (long)blockIdx.x * blockDim.x + threadIdx.x; i < n4; i += (long)gridDim.x * blockDim.x) {
    float4 v = ((const float4*)in)[i];
    ushort4 o4 = { f2bf(v.x), f2bf(v.y), f2bf(v.z), f2bf(v.w) };
    ((ushort4*)out)[i] = o4;
  }
}

// h = embed[ids[s]] * sqrt(H); x = bf16(rms(h, ln1))
__global__ void gather_rms_kernel(const int* __restrict__ ids, const float* __restrict__ embed,
                                  const float* __restrict__ w, float* __restrict__ h,
                                  u16* __restrict__ x) {
  __shared__ float red[8];
  const int s = blockIdx.x, t = threadIdx.x;
  const float* src = embed + (size_t)ids[s] * 640;
  const float scale = sqrtf(640.0f);
  float hv[3];
  float ss = 0.0f;
#pragma unroll
  for (int i = 0; i < 3; ++i) {
    int c = t + i * 256;
    float v = (c < 640) ? src[c] * scale : 0.0f;
    hv[i] = v; ss += v * v;
  }
  ss = blockSum(ss, red);
  const float sc = rsqrtf(ss * (1.0f / 640.0f) + 1e-6f);
#pragma unroll
  for (int i = 0; i < 3; ++i) {
    int c = t + i * 256;
    if (c < 640) {
      h[(size_t)s * 640 + c] = hv[i];
      x[(size_t)s * 640 + c] = f2bf(hv[i] * sc * (1.0f + w[c]));
    }
  }
}

// h += rms(sum_z t1[z], wa); xout = bf16(rms(h, wn))
__global__ void fused_add_norm(float* __restrict__ h, const float* __restrict__ t1,
                               int nsl, const float* __restrict__ wa,
                               const float* __restrict__ wn, u16* __restrict__ xout) {
  __shared__ float red[8];
  const int row = blockIdx.x, t = threadIdx.x;
  float ts[3], hv[3];
  float ss = 0.0f;
#pragma unroll
  for (int i = 0; i < 3; ++i) {
    int c = t + i * 256;
    float v = 0.0f;
    if (c < 640) {
      v = t1[(size_t)row * 640 + c];
      for (int z = 1; z < nsl; ++z) v += t1[(size_t)z * 655360 + (size_t)row * 640 + c];
    }
    ts[i] = v; ss += v * v;
  }
  ss = blockSum(ss, red);
  const float s1 = rsqrtf(ss * (1.0f / 640.0f) + 1e-6f);
  float ss2 = 0.0f;
#pragma unroll
  for (int i = 0; i < 3; ++i) {
    int c = t + i * 256;
    float v = 0.0f;
    if (c < 640) v = h[(size_t)row * 640 + c] + ts[i] * s1 * (1.0f + wa[c]);
    hv[i] = v; ss2 += v * v;
  }
  ss2 = blockSum(ss2, red);
  const float s2 = rsqrtf(ss2 * (1.0f / 640.0f) + 1e-6f);
#pragma unroll
  for (int i = 0; i < 3; ++i) {
    int c = t + i * 256;
    if (c < 640) {
      h[(size_t)row * 640 + c] = hv[i];
      xout[(size_t)row * 640 + c] = f2bf(hv[i] * s2 * (1.0f + wn[c]));
    }
  }
}

__global__ void rope_tables_kernel(float* cg, float* sg, float* cl, float* sl) {
  int s = blockIdx.x, t = threadIdx.x;  // t < 128
  float e = -(float)t * (1.0f / 128.0f);
  float ag = (float)s * expf(e * logf(1000000.0f));
  float al = (float)s * expf(e * logf(10000.0f));
  cg[s * 128 + t] = cosf(ag); sg[s * 128 + t] = sinf(ag);
  cl[s * 128 + t] = cosf(al); sl[s * 128 + t] = sinf(al);
}

// per (s, unit): unit 0..3 Q heads (rms+rope), 4 K (rms+rope), 5 V transpose.
// qkvf has 2 split-K slices (stride S*1536) summed here (r8-proven).
__global__ void rope_fused(const float* __restrict__ qkvf, const float* __restrict__ qn,
                           const float* __restrict__ kn, u16* __restrict__ qb,
                           u16* __restrict__ kb, u16* __restrict__ vt,
                           const float* __restrict__ ct, const float* __restrict__ st) {
  __shared__ float red[8];
  __shared__ float sh[256];
  const int s = blockIdx.x, hh = blockIdx.y, t = threadIdx.x;
  const long SL = (long)1024 * 1536;
  if (hh == 5) {
    long i = (size_t)s * 1536 + 1280 + t;
    vt[(size_t)t * 1024 + s] = f2bf(qkvf[i] + qkvf[i + SL]);
    return;
  }
  long i = (size_t)s * 1536 + hh * 256 + t;  // hh==4 -> K at 1024
  const float* nw = (hh == 4) ? kn : qn;
  float x = qkvf[i] + qkvf[i + SL];
  float ss = blockSum(x * x, red);
  float n = x * rsqrtf(ss * (1.0f / 256.0f) + 1e-6f) * (1.0f + nw[t]);
  sh[t] = n;
  __syncthreads();
  float cosv = ct[s * 128 + (t & 127)];
  float sinv = st[s * 128 + (t & 127)];
  float partner = (t < 128) ? -sh[t + 128] : sh[t - 128];
  u16 r = f2bf(n * cosv + partner * sinv);
  if (hh == 4) kb[(size_t)s * 256 + t] = r;
  else qb[((size_t)hh * 1024 + s) * 256 + t] = r;
}

// masked softmax; writes P over exactly the band PV reads. mode 1 sliding, 0 causal
__global__ void softmax_kernel(const float* __restrict__ sc, u16* __restrict__ P, int mode) {
  __shared__ float red[8];
  const int i = blockIdx.x, hh = blockIdx.y, t = threadIdx.x;
  const float* row = sc + ((size_t)hh * 1024 + i) * 1024;
  u16* prow = P + ((size_t)hh * 1024 + i) * 1024;
  const int m0 = i & ~127;
  int lo = 0, wlo = 0;
  if (mode) {
    lo = i - 511; if (lo < 0) lo = 0;
    wlo = m0 - 512; if (wlo < 0) wlo = 0;
  }
  const int whi = m0 + 127;
  float m = -1e30f;
  for (int j = lo + t; j <= i; j += 256) m = fmaxf(m, row[j]);
  m = blockMax(m, red);
  float sum = 0.0f;
  for (int j = lo + t; j <= i; j += 256) sum += __expf(row[j] - m);
  sum = blockSum(sum, red);
  float inv = 1.0f / sum;
  for (int j = wlo + t; j <= whi; j += 256) {
    float v = (j >= lo && j <= i) ? __expf(row[j] - m) * inv : 0.0f;
    prow[j] = f2bf(v);
  }
}

// transpose + bf16-convert 7 per-layer weights; 64x64 tiles.
// wg/wu interleave into wguT rows at 16-col granularity (g: rows r&31<16, u: >=16).
__global__ void transpose7_kernel(
    const float* s0, const float* s1, const float* s2, const float* s3,
    const float* s4, const float* s5, const float* s6,
    u16* d0, u16* d1, u16* d2, u16* d3, u16* d45, u16* d6) {
  __shared__ float tile[64][65];
  int b = blockIdx.x;
  const float* src; u16* dst; int K, N, idx, ilv = 0;
  if (b < 160)       { src = s0; dst = d0;  K = 640;  N = 1024; idx = b; }
  else if (b < 200)  { src = s1; dst = d1;  K = 640;  N = 256;  idx = b - 160; }
  else if (b < 240)  { src = s2; dst = d2;  K = 640;  N = 256;  idx = b - 200; }
  else if (b < 400)  { src = s3; dst = d3;  K = 1024; N = 640;  idx = b - 240; }
  else if (b < 720)  { src = s4; dst = d45; K = 640;  N = 2048; idx = b - 400;  ilv = 1; }
  else if (b < 1040) { src = s5; dst = d45; K = 640;  N = 2048; idx = b - 720;  ilv = 2; }
  else               { src = s6; dst = d6;  K = 2048; N = 640;  idx = b - 1040; }
  int tn = N >> 6;
  int kt = idx / tn, nt = idx % tn;
  int t = threadIdx.x;
  int lr = t >> 4, lc = (t & 15) * 4;
#pragma unroll
  for (int i = 0; i < 4; ++i) {
    float4 v = *(const float4*)&src[(size_t)(kt * 64 + lr + i * 16) * N + nt * 64 + lc];
    tile[lr + i * 16][lc] = v.x; tile[lr + i * 16][lc + 1] = v.y;
    tile[lr + i * 16][lc + 2] = v.z; tile[lr + i * 16][lc + 3] = v.w;
  }
  __syncthreads();
  int wn = t >> 3, wk8 = (t & 7) * 8;
#pragma unroll
  for (int i = 0; i < 2; ++i) {
    int gcol = nt * 64 + wn + i * 32;
    int drow = ilv ? ((gcol >> 4) * 32 + ((ilv == 2) ? 16 : 0) + (gcol & 15)) : gcol;
    u16 tmp[8];
#pragma unroll
    for (int j = 0; j < 8; ++j) tmp[j] = f2bf(tile[wk8 + j][wn + i * 32]);
    *(int4*)&dst[(size_t)drow * K + kt * 64 + wk8] = *(int4*)tmp;
  }
}

extern "C" void kernel_launch(void* const* d_in, const int* in_sizes, int n_in,
                              void* d_out, int out_size, void* d_ws, size_t ws_size,
                              hipStream_t stream) {
  (void)in_sizes; (void)n_in; (void)out_size; (void)ws_size;
  const int*   ids   = (const int*)d_in[0];
  // d_in[1] = is_full; deterministic (l+1)%6==0, hardcoded.
  const float* embed = (const float*)d_in[2];
  const float* wq    = (const float*)d_in[3];
  const float* wk    = (const float*)d_in[4];
  const float* wv    = (const float*)d_in[5];
  const float* wo    = (const float*)d_in[6];
  const float* qn    = (const float*)d_in[7];
  const float* kn    = (const float*)d_in[8];
  const float* ln1   = (const float*)d_in[9];
  const float* ln2   = (const float*)d_in[10];
  const float* ln3   = (const float*)d_in[11];
  const float* ln4   = (const float*)d_in[12];
  const float* wg    = (const float*)d_in[13];
  const float* wu    = (const float*)d_in[14];
  const float* wd    = (const float*)d_in[15];
  const float* nw    = (const float*)d_in[16];
  float* out = (float*)d_out;

  const int S = 1024, H = 640, NH = 4, HD = 256, I = 2048, V = 32768;

  unsigned char* p = (unsigned char*)d_ws;
  auto alloc = [&](size_t b) { void* r = (void*)p; p += (b + 255) & ~(size_t)255; return r; };
  u16*   wqkvT = (u16*)alloc((size_t)1536 * 640 * 2);
  u16*   woT   = (u16*)alloc((size_t)640 * 1024 * 2);
  u16*   wguT  = (u16*)alloc((size_t)4096 * 640 * 2);   // g/u interleaved rows
  u16*   wdT   = (u16*)alloc((size_t)640 * 2048 * 2);
  u16*   embT  = (u16*)alloc((size_t)V * H * 2);
  float* h     = (float*)alloc((size_t)S * H * 4);
  u16*   x     = (u16*)alloc((size_t)S * H * 2);
  float* qkvf  = (float*)alloc((size_t)2 * S * 1536 * 4);  // 2 split-K slices
  u16*   qb    = (u16*)alloc((size_t)NH * S * HD * 2);
  u16*   kb    = (u16*)alloc((size_t)S * HD * 2);
  u16*   vt    = (u16*)alloc((size_t)HD * S * 2);
  float* scp   = (float*)alloc((size_t)NH * S * S * 4);
  u16*   P     = (u16*)alloc((size_t)NH * S * S * 2);
  u16*   o     = (u16*)alloc((size_t)S * NH * HD * 2);
  float* t1    = (float*)alloc((size_t)8 * S * H * 4);  // up to 8 split-K slices
  u16*   mg    = (u16*)alloc((size_t)S * I * 2);
  u16*   hn    = (u16*)alloc((size_t)S * H * 2);
  float* cg    = (float*)alloc((size_t)S * 128 * 4);
  float* sg    = (float*)alloc((size_t)S * 128 * 4);
  float* cl    = (float*)alloc((size_t)S * 128 * 4);
  float* sl2   = (float*)alloc((size_t)S * 128 * 4);

  rope_tables_kernel<<<S, 128, 0, stream>>>(cg, sg, cl, sl2);
  conv_bf16_kernel<<<2048, 256, 0, stream>>>(embed, embT, (long)V * H / 4);
  gather_rms_kernel<<<S, 256, 0, stream>>>(ids, embed, ln1, h, x);

  for (int l = 0; l < 18; ++l) {
    bool full = ((l + 1) % 6) == 0;

    transpose7_kernel<<<1360, 256, 0, stream>>>(
        wq + (size_t)l * H * 1024, wk + (size_t)l * H * 256, wv + (size_t)l * H * 256,
        wo + (size_t)l * 1024 * H, wg + (size_t)l * H * I, wu + (size_t)l * H * I,
        wd + (size_t)l * I * H,
        wqkvT, wqkvT + (size_t)1024 * 640, wqkvT + (size_t)1280 * 640, woT, wguT, wdT);

    // QKV split-K=2: 192 blocks, slices summed in rope_fused
    gemm_nt<float, 0, 64><<<dim3(12, 8, 2), 256, 0, stream>>>(
        x, H, 0, wqkvT, H, 0, qkvf, 1536, (long)S * 1536, H, 1.0f, 3, -1, 2);
    rope_fused<<<dim3(S, 6), 256, 0, stream>>>(qkvf, qn + l * HD, kn + l * HD, qb, kb, vt,
                                               full ? cg : cl, full ? sg : sl2);
    if (full)
      gemm_nt<float, 0, 64><<<dim3(8, 8, NH), 256, 0, stream>>>(
          qb, HD, (long)S * HD, kb, HD, 0, scp, S, (long)S * S, HD, 0.0625f, 0, -2, 1);
    else
      gemm_nt<float, 0, 64><<<dim3(5, 8, NH), 256, 0, stream>>>(
          qb, HD, (long)S * HD, kb, HD, 0, scp, S, (long)S * S, HD, 0.0625f, 0, 512, 1);
    softmax_kernel<<<dim3(S, NH), 256, 0, stream>>>(scp, P, full ? 0 : 1);
    gemm_nt<u16, 0, 64><<<dim3(2, 8, NH), 256, 0, stream>>>(
        P, S, (long)S * S, vt, S, 0, o, NH * HD, HD, S, 1.0f, full ? 2 : 1, -1, 1);
    // wo split-K=4: 160 blocks
    gemm_nt<float, 0, 64><<<dim3(5, 8, 4), 256, 0, stream>>>(
        o, NH * HD, 0, woT, NH * HD, 0, t1, H, (long)S * H, NH * HD, 1.0f, 3, -1, 4);
    fused_add_norm<<<S, 256, 0, stream>>>(h, t1, 4, ln2 + l * H, ln3 + l * H, x);

    gemm_nt<u16, 1, 64><<<dim3(32, 8, 1), 256, 0, stream>>>(
        x, H, 0, wguT, H, 0, mg, I, 0, H, 1.0f, 0, -1, 1);
    // wd split-K=8: 320 blocks
    gemm_nt<float, 0, 64><<<dim3(5, 8, 8), 256, 0, stream>>>(
        mg, I, 0, wdT, I, 0, t1, H, (long)S * H, I, 1.0f, 3, -1, 8);
    fused_add_norm<<<S, 256, 0, stream>>>(h, t1, 8, ln4 + l * H,
                                          (l == 17) ? nw : ln1 + (l + 1) * H,
                                          (l == 17) ? hn : x);
  }

  // logits = hn @ embT^T — BK=32 variant (conflict-free swizzle)
  gemm_nt<float, 0, 32><<<dim3(V / 128, 8, 1), 256, 0, stream>>>(
      hn, H, 0, embT, H, 0, out, V, 0, H, 1.0f, 0, -1, 1);
}

// Round 17
// 2017.517 us; speedup vs baseline: 1.0110x; 1.0110x over previous
//
#include <hip/hip_runtime.h>

// Gemma3 forward, MI355X. Round 17: round-15 champion restored (best measured:
// 2018 us). QKV split-K=2, wo split-K=2, wd split-K=4, BK=32 logits.
// r16's deeper split-K (wo=4/wd=8) regressed (+22 us) — traffic > latency gain.
// L=18 H=640 NH=4 NKV=1 HD=256 I=2048 V=32768 B=1 S=1024 WINDOW=512

typedef unsigned short u16;
typedef __attribute__((ext_vector_type(4))) float f32x4;
typedef __attribute__((ext_vector_type(8))) short bf16x8;

#define DEV static __device__ __forceinline__

DEV u16 f2bf(float f) {  // round-to-nearest-even fp32 -> bf16
  union { float f; unsigned u; } x; x.f = f;
  unsigned r = x.u + 0x7fffu + ((x.u >> 16) & 1u);
  return (u16)(r >> 16);
}

#define GLOAD16(gp, lp) __builtin_amdgcn_global_load_lds( \
    (const __attribute__((address_space(1))) void*)(gp), \
    (__attribute__((address_space(3))) void*)(lp), 16, 0, 0)

DEV float blockSum(float v, float* red) {
#pragma unroll
  for (int o = 32; o; o >>= 1) v += __shfl_down(v, o);
  int lane = threadIdx.x & 63, wid = threadIdx.x >> 6;
  if (lane == 0) red[wid] = v;
  __syncthreads();
  float s = red[0] + red[1] + red[2] + red[3];
  __syncthreads();
  return s;
}

DEV float blockMax(float v, float* red) {
#pragma unroll
  for (int o = 32; o; o >>= 1) v = fmaxf(v, __shfl_down(v, o));
  int lane = threadIdx.x & 63, wid = threadIdx.x >> 6;
  if (lane == 0) red[wid] = v;
  __syncthreads();
  float s = fmaxf(fmaxf(red[0], red[1]), fmaxf(red[2], red[3]));
  __syncthreads();
  return s;
}

DEV void cstore(float* C, size_t i, float v) { C[i] = v; }
DEV void cstore(u16* C, size_t i, float v) { C[i] = f2bf(v); }

// ---- GEMM NT: C[M,N] = alpha * A[M,K]bf16 * (B[N,K]bf16)^T ----
// 128x128 tile. BKT=64: swizzle key row&7 (proven). BKT=32: 32KB LDS,
// swizzle key (row>>1)&3 (conflict-free, proven r13/r14). Double-buffered
// LDS, depth-1 prefetch via global_load_lds, pre-swizzled source column.
// nshift: -1 plain; -2 causal tile-skip; >=0 sliding band n0=m0-nshift+bx*128.
// kmode: 0 full K; 1 sliding K-band; 2 causal K-band; 3 split-K over blockIdx.z.
// GEGLU=1: B rows g/u-interleaved at 16-col granularity.
template <typename CT, int GEGLU, int BKT>
__global__ __launch_bounds__(256) void gemm_nt(
    const u16* __restrict__ A, int lda, long sA,
    const u16* __restrict__ B, int ldb, long sB,
    CT* __restrict__ C, int ldc, long sC,
    int K, float alpha, int kmode, int nshift, int ksplit) {
  constexpr int DB = 128 * BKT;             // elems per LDS buffer
  __shared__ __align__(16) u16 As[2 * DB];
  __shared__ __align__(16) u16 Bs[2 * DB];
  const int m0 = blockIdx.y * 128;
  int n0;
  if (nshift == -1) n0 = blockIdx.x * 128;
  else if (nshift == -2) { n0 = blockIdx.x * 128; if (n0 > m0) return; }
  else { n0 = m0 - nshift + blockIdx.x * 128; if (n0 < 0) return; }
  int klo = 0, khi = K;
  if (kmode == 1) { klo = m0 - 512; if (klo < 0) klo = 0; khi = m0 + 128; if (khi > K) khi = K; }
  else if (kmode == 2) { khi = m0 + 128; if (khi > K) khi = K; }
  else if (kmode == 3) { int kl = K / ksplit; klo = blockIdx.z * kl; khi = klo + kl; }
  A += (long)blockIdx.z * sA;
  B += (long)blockIdx.z * sB;

  const int t = threadIdx.x;
  const int l = t & 63, w = t >> 6;
  const int wr = w >> 1, wc = w & 1;        // 2x2 waves, each 64x64 out
  const int lr = l & 15, lk = l >> 4;
  const int srow = (BKT == 64) ? (t >> 3) : (t >> 2);
  const int scolx = (BKT == 64) ? (((t & 7) ^ (srow & 7)) << 3)
                                : (((t & 3) ^ ((srow >> 1) & 3)) << 3);
  const u16* Ag = A + (size_t)(m0 + srow) * lda + scolx;
  const u16* Bg = B + (size_t)(n0 + srow) * ldb + scolx;
  const int nsteps = (khi - klo) / BKT;

  auto stage = [&](int db, int k0) {
    u16* al = As + db * DB + w * 512;       // wave-uniform LDS bases
    u16* bl = Bs + db * DB + w * 512;
    if constexpr (BKT == 64) {
#pragma unroll
      for (int p = 0; p < 4; ++p) {         // rows p*32 + srow(0..31)
        GLOAD16(Ag + k0 + (size_t)(32 * p) * lda, al + p * 2048);
        GLOAD16(Bg + k0 + (size_t)(32 * p) * ldb, bl + p * 2048);
      }
    } else {
#pragma unroll
      for (int p = 0; p < 2; ++p) {         // rows p*64 + srow(0..63)
        GLOAD16(Ag + k0 + (size_t)(64 * p) * lda, al + p * 2048);
        GLOAD16(Bg + k0 + (size_t)(64 * p) * ldb, bl + p * 2048);
      }
    }
  };

  stage(0, klo);
  f32x4 acc[4][4] = {};

  for (int s = 0; s < nsteps; ++s) {
    __syncthreads();                        // drains prefetch; joins prior ds_reads
    const int db = s & 1;
    if (s + 1 < nsteps) stage(db ^ 1, klo + (s + 1) * BKT);
    const u16* Ab = As + db * DB;
    const u16* Bb = Bs + db * DB;
    if constexpr (BKT == 64) {
      const int axr = lr & 7;
      bf16x8 af[2][4], bfr[2][4];
#pragma unroll
      for (int kk = 0; kk < 2; ++kk)
#pragma unroll
        for (int i = 0; i < 4; ++i) {
          af[kk][i]  = *(const bf16x8*)&Ab[(wr * 64 + i * 16 + lr) * 64 + (((kk * 4 + lk) ^ axr) << 3)];
          bfr[kk][i] = *(const bf16x8*)&Bb[(wc * 64 + i * 16 + lr) * 64 + (((kk * 4 + lk) ^ axr) << 3)];
        }
#pragma unroll
      for (int kk = 0; kk < 2; ++kk)
#pragma unroll
        for (int mi = 0; mi < 4; ++mi)
#pragma unroll
          for (int ni = 0; ni < 4; ++ni)
            acc[mi][ni] = __builtin_amdgcn_mfma_f32_16x16x32_bf16(af[kk][mi], bfr[kk][ni], acc[mi][ni], 0, 0, 0);
    } else {
      const int key = (lr >> 1) & 3;        // (row>>1)&3; i*16 offsets drop out
      bf16x8 af[4], bfr[4];
#pragma unroll
      for (int i = 0; i < 4; ++i) {
        af[i]  = *(const bf16x8*)&Ab[(wr * 64 + i * 16 + lr) * 32 + ((lk ^ key) << 3)];
        bfr[i] = *(const bf16x8*)&Bb[(wc * 64 + i * 16 + lr) * 32 + ((lk ^ key) << 3)];
      }
#pragma unroll
      for (int mi = 0; mi < 4; ++mi)
#pragma unroll
        for (int ni = 0; ni < 4; ++ni)
          acc[mi][ni] = __builtin_amdgcn_mfma_f32_16x16x32_bf16(af[mi], bfr[ni], acc[mi][ni], 0, 0, 0);
    }
  }

  C += (long)blockIdx.z * sC;
  if (GEGLU) {
    // acc[ni]: B rows n0+wc*64+ni*16+lr; rows (r&31)<16 are g, >=16 are u.
#pragma unroll
    for (int mi = 0; mi < 4; ++mi) {
      int row = m0 + wr * 64 + mi * 16 + lk * 4;
#pragma unroll
      for (int np = 0; np < 2; ++np) {
        int col = (n0 + wc * 64) / 2 + np * 16 + lr;
#pragma unroll
        for (int j = 0; j < 4; ++j) {
          float g = acc[mi][2 * np][j], u = acc[mi][2 * np + 1][j];
          float z = 0.7978845608028654f * (g + 0.044715f * g * g * g);
          float th = 2.0f / (1.0f + __expf(-2.0f * z)) - 1.0f;
          cstore(C, (size_t)(row + j) * ldc + col, 0.5f * g * (1.0f + th) * u);
        }
      }
    }
  } else {
#pragma unroll
    for (int mi = 0; mi < 4; ++mi) {
      int row = m0 + wr * 64 + mi * 16 + lk * 4;
#pragma unroll
      for (int ni = 0; ni < 4; ++ni) {
        int col = n0 + wc * 64 + ni * 16 + lr;
#pragma unroll
        for (int j = 0; j < 4; ++j)
          cstore(C, (size_t)(row + j) * ldc + col, acc[mi][ni][j] * alpha);
      }
    }
  }
}

// ---- small kernels ----
__global__ void conv_bf16_kernel(const float* __restrict__ in, u16* __restrict__ out, long n4) {
  for (long i = (long)blockIdx.x * blockDim.x + threadIdx.x; i < n4; i += (long)gridDim.x * blockDim.x) {
    float4 v = ((const float4*)in)[i];
    ushort4 o4 = { f2bf(v.x), f2bf(v.y), f2bf(v.z), f2bf(v.w) };
    ((ushort4*)out)[i] = o4;
  }
}

// h = embed[ids[s]] * sqrt(H); x = bf16(rms(h, ln1))
__global__ void gather_rms_kernel(const int* __restrict__ ids, const float* __restrict__ embed,
                                  const float* __restrict__ w, float* __restrict__ h,
                                  u16* __restrict__ x) {
  __shared__ float red[8];
  const int s = blockIdx.x, t = threadIdx.x;
  const float* src = embed + (size_t)ids[s] * 640;
  const float scale = sqrtf(640.0f);
  float hv[3];
  float ss = 0.0f;
#pragma unroll
  for (int i = 0; i < 3; ++i) {
    int c = t + i * 256;
    float v = (c < 640) ? src[c] * scale : 0.0f;
    hv[i] = v; ss += v * v;
  }
  ss = blockSum(ss, red);
  const float sc = rsqrtf(ss * (1.0f / 640.0f) + 1e-6f);
#pragma unroll
  for (int i = 0; i < 3; ++i) {
    int c = t + i * 256;
    if (c < 640) {
      h[(size_t)s * 640 + c] = hv[i];
      x[(size_t)s * 640 + c] = f2bf(hv[i] * sc * (1.0f + w[c]));
    }
  }
}

// h += rms(sum_z t1[z], wa); xout = bf16(rms(h, wn))
__global__ void fused_add_norm(float* __restrict__ h, const float* __restrict__ t1,
                               int nsl, const float* __restrict__ wa,
                               const float* __restrict__ wn, u16* __restrict__ xout) {
  __shared__ float red[8];
  const int row = blockIdx.x, t = threadIdx.x;
  float ts[3], hv[3];
  float ss = 0.0f;
#pragma unroll
  for (int i = 0; i < 3; ++i) {
    int c = t + i * 256;
    float v = 0.0f;
    if (c < 640) {
      v = t1[(size_t)row * 640 + c];
      for (int z = 1; z < nsl; ++z) v += t1[(size_t)z * 655360 + (size_t)row * 640 + c];
    }
    ts[i] = v; ss += v * v;
  }
  ss = blockSum(ss, red);
  const float s1 = rsqrtf(ss * (1.0f / 640.0f) + 1e-6f);
  float ss2 = 0.0f;
#pragma unroll
  for (int i = 0; i < 3; ++i) {
    int c = t + i * 256;
    float v = 0.0f;
    if (c < 640) v = h[(size_t)row * 640 + c] + ts[i] * s1 * (1.0f + wa[c]);
    hv[i] = v; ss2 += v * v;
  }
  ss2 = blockSum(ss2, red);
  const float s2 = rsqrtf(ss2 * (1.0f / 640.0f) + 1e-6f);
#pragma unroll
  for (int i = 0; i < 3; ++i) {
    int c = t + i * 256;
    if (c < 640) {
      h[(size_t)row * 640 + c] = hv[i];
      xout[(size_t)row * 640 + c] = f2bf(hv[i] * s2 * (1.0f + wn[c]));
    }
  }
}

__global__ void rope_tables_kernel(float* cg, float* sg, float* cl, float* sl) {
  int s = blockIdx.x, t = threadIdx.x;  // t < 128
  float e = -(float)t * (1.0f / 128.0f);
  float ag = (float)s * expf(e * logf(1000000.0f));
  float al = (float)s * expf(e * logf(10000.0f));
  cg[s * 128 + t] = cosf(ag); sg[s * 128 + t] = sinf(ag);
  cl[s * 128 + t] = cosf(al); sl[s * 128 + t] = sinf(al);
}

// per (s, unit): unit 0..3 Q heads (rms+rope), 4 K (rms+rope), 5 V transpose.
// qkvf has 2 split-K slices (stride S*1536) summed here (r8-proven).
__global__ void rope_fused(const float* __restrict__ qkvf, const float* __restrict__ qn,
                           const float* __restrict__ kn, u16* __restrict__ qb,
                           u16* __restrict__ kb, u16* __restrict__ vt,
                           const float* __restrict__ ct, const float* __restrict__ st) {
  __shared__ float red[8];
  __shared__ float sh[256];
  const int s = blockIdx.x, hh = blockIdx.y, t = threadIdx.x;
  const long SL = (long)1024 * 1536;
  if (hh == 5) {
    long i = (size_t)s * 1536 + 1280 + t;
    vt[(size_t)t * 1024 + s] = f2bf(qkvf[i] + qkvf[i + SL]);
    return;
  }
  long i = (size_t)s * 1536 + hh * 256 + t;  // hh==4 -> K at 1024
  const float* nw = (hh == 4) ? kn : qn;
  float x = qkvf[i] + qkvf[i + SL];
  float ss = blockSum(x * x, red);
  float n = x * rsqrtf(ss * (1.0f / 256.0f) + 1e-6f) * (1.0f + nw[t]);
  sh[t] = n;
  __syncthreads();
  float cosv = ct[s * 128 + (t & 127)];
  float sinv = st[s * 128 + (t & 127)];
  float partner = (t < 128) ? -sh[t + 128] : sh[t - 128];
  u16 r = f2bf(n * cosv + partner * sinv);
  if (hh == 4) kb[(size_t)s * 256 + t] = r;
  else qb[((size_t)hh * 1024 + s) * 256 + t] = r;
}

// masked softmax; writes P over exactly the band PV reads. mode 1 sliding, 0 causal
__global__ void softmax_kernel(const float* __restrict__ sc, u16* __restrict__ P, int mode) {
  __shared__ float red[8];
  const int i = blockIdx.x, hh = blockIdx.y, t = threadIdx.x;
  const float* row = sc + ((size_t)hh * 1024 + i) * 1024;
  u16* prow = P + ((size_t)hh * 1024 + i) * 1024;
  const int m0 = i & ~127;
  int lo = 0, wlo = 0;
  if (mode) {
    lo = i - 511; if (lo < 0) lo = 0;
    wlo = m0 - 512; if (wlo < 0) wlo = 0;
  }
  const int whi = m0 + 127;
  float m = -1e30f;
  for (int j = lo + t; j <= i; j += 256) m = fmaxf(m, row[j]);
  m = blockMax(m, red);
  float sum = 0.0f;
  for (int j = lo + t; j <= i; j += 256) sum += __expf(row[j] - m);
  sum = blockSum(sum, red);
  float inv = 1.0f / sum;
  for (int j = wlo + t; j <= whi; j += 256) {
    float v = (j >= lo && j <= i) ? __expf(row[j] - m) * inv : 0.0f;
    prow[j] = f2bf(v);
  }
}

// transpose + bf16-convert 7 per-layer weights; 64x64 tiles.
// wg/wu interleave into wguT rows at 16-col granularity (g: rows r&31<16, u: >=16).
__global__ void transpose7_kernel(
    const float* s0, const float* s1, const float* s2, const float* s3,
    const float* s4, const float* s5, const float* s6,
    u16* d0, u16* d1, u16* d2, u16* d3, u16* d45, u16* d6) {
  __shared__ float tile[64][65];
  int b = blockIdx.x;
  const float* src; u16* dst; int K, N, idx, ilv = 0;
  if (b < 160)       { src = s0; dst = d0;  K = 640;  N = 1024; idx = b; }
  else if (b < 200)  { src = s1; dst = d1;  K = 640;  N = 256;  idx = b - 160; }
  else if (b < 240)  { src = s2; dst = d2;  K = 640;  N = 256;  idx = b - 200; }
  else if (b < 400)  { src = s3; dst = d3;  K = 1024; N = 640;  idx = b - 240; }
  else if (b < 720)  { src = s4; dst = d45; K = 640;  N = 2048; idx = b - 400;  ilv = 1; }
  else if (b < 1040) { src = s5; dst = d45; K = 640;  N = 2048; idx = b - 720;  ilv = 2; }
  else               { src = s6; dst = d6;  K = 2048; N = 640;  idx = b - 1040; }
  int tn = N >> 6;
  int kt = idx / tn, nt = idx % tn;
  int t = threadIdx.x;
  int lr = t >> 4, lc = (t & 15) * 4;
#pragma unroll
  for (int i = 0; i < 4; ++i) {
    float4 v = *(const float4*)&src[(size_t)(kt * 64 + lr + i * 16) * N + nt * 64 + lc];
    tile[lr + i * 16][lc] = v.x; tile[lr + i * 16][lc + 1] = v.y;
    tile[lr + i * 16][lc + 2] = v.z; tile[lr + i * 16][lc + 3] = v.w;
  }
  __syncthreads();
  int wn = t >> 3, wk8 = (t & 7) * 8;
#pragma unroll
  for (int i = 0; i < 2; ++i) {
    int gcol = nt * 64 + wn + i * 32;
    int drow = ilv ? ((gcol >> 4) * 32 + ((ilv == 2) ? 16 : 0) + (gcol & 15)) : gcol;
    u16 tmp[8];
#pragma unroll
    for (int j = 0; j < 8; ++j) tmp[j] = f2bf(tile[wk8 + j][wn + i * 32]);
    *(int4*)&dst[(size_t)drow * K + kt * 64 + wk8] = *(int4*)tmp;
  }
}

extern "C" void kernel_launch(void* const* d_in, const int* in_sizes, int n_in,
                              void* d_out, int out_size, void* d_ws, size_t ws_size,
                              hipStream_t stream) {
  (void)in_sizes; (void)n_in; (void)out_size; (void)ws_size;
  const int*   ids   = (const int*)d_in[0];
  // d_in[1] = is_full; deterministic (l+1)%6==0, hardcoded.
  const float* embed = (const float*)d_in[2];
  const float* wq    = (const float*)d_in[3];
  const float* wk    = (const float*)d_in[4];
  const float* wv    = (const float*)d_in[5];
  const float* wo    = (const float*)d_in[6];
  const float* qn    = (const float*)d_in[7];
  const float* kn    = (const float*)d_in[8];
  const float* ln1   = (const float*)d_in[9];
  const float* ln2   = (const float*)d_in[10];
  const float* ln3   = (const float*)d_in[11];
  const float* ln4   = (const float*)d_in[12];
  const float* wg    = (const float*)d_in[13];
  const float* wu    = (const float*)d_in[14];
  const float* wd    = (const float*)d_in[15];
  const float* nw    = (const float*)d_in[16];
  float* out = (float*)d_out;

  const int S = 1024, H = 640, NH = 4, HD = 256, I = 2048, V = 32768;

  unsigned char* p = (unsigned char*)d_ws;
  auto alloc = [&](size_t b) { void* r = (void*)p; p += (b + 255) & ~(size_t)255; return r; };
  u16*   wqkvT = (u16*)alloc((size_t)1536 * 640 * 2);
  u16*   woT   = (u16*)alloc((size_t)640 * 1024 * 2);
  u16*   wguT  = (u16*)alloc((size_t)4096 * 640 * 2);   // g/u interleaved rows
  u16*   wdT   = (u16*)alloc((size_t)640 * 2048 * 2);
  u16*   embT  = (u16*)alloc((size_t)V * H * 2);
  float* h     = (float*)alloc((size_t)S * H * 4);
  u16*   x     = (u16*)alloc((size_t)S * H * 2);
  float* qkvf  = (float*)alloc((size_t)2 * S * 1536 * 4);  // 2 split-K slices
  u16*   qb    = (u16*)alloc((size_t)NH * S * HD * 2);
  u16*   kb    = (u16*)alloc((size_t)S * HD * 2);
  u16*   vt    = (u16*)alloc((size_t)HD * S * 2);
  float* scp   = (float*)alloc((size_t)NH * S * S * 4);
  u16*   P     = (u16*)alloc((size_t)NH * S * S * 2);
  u16*   o     = (u16*)alloc((size_t)S * NH * HD * 2);
  float* t1    = (float*)alloc((size_t)4 * S * H * 4);  // up to 4 split-K slices
  u16*   mg    = (u16*)alloc((size_t)S * I * 2);
  u16*   hn    = (u16*)alloc((size_t)S * H * 2);
  float* cg    = (float*)alloc((size_t)S * 128 * 4);
  float* sg    = (float*)alloc((size_t)S * 128 * 4);
  float* cl    = (float*)alloc((size_t)S * 128 * 4);
  float* sl2   = (float*)alloc((size_t)S * 128 * 4);

  rope_tables_kernel<<<S, 128, 0, stream>>>(cg, sg, cl, sl2);
  conv_bf16_kernel<<<2048, 256, 0, stream>>>(embed, embT, (long)V * H / 4);
  gather_rms_kernel<<<S, 256, 0, stream>>>(ids, embed, ln1, h, x);

  for (int l = 0; l < 18; ++l) {
    bool full = ((l + 1) % 6) == 0;

    transpose7_kernel<<<1360, 256, 0, stream>>>(
        wq + (size_t)l * H * 1024, wk + (size_t)l * H * 256, wv + (size_t)l * H * 256,
        wo + (size_t)l * 1024 * H, wg + (size_t)l * H * I, wu + (size_t)l * H * I,
        wd + (size_t)l * I * H,
        wqkvT, wqkvT + (size_t)1024 * 640, wqkvT + (size_t)1280 * 640, woT, wguT, wdT);

    // QKV split-K=2: 192 blocks, slices summed in rope_fused
    gemm_nt<float, 0, 64><<<dim3(12, 8, 2), 256, 0, stream>>>(
        x, H, 0, wqkvT, H, 0, qkvf, 1536, (long)S * 1536, H, 1.0f, 3, -1, 2);
    rope_fused<<<dim3(S, 6), 256, 0, stream>>>(qkvf, qn + l * HD, kn + l * HD, qb, kb, vt,
                                               full ? cg : cl, full ? sg : sl2);
    if (full)
      gemm_nt<float, 0, 64><<<dim3(8, 8, NH), 256, 0, stream>>>(
          qb, HD, (long)S * HD, kb, HD, 0, scp, S, (long)S * S, HD, 0.0625f, 0, -2, 1);
    else
      gemm_nt<float, 0, 64><<<dim3(5, 8, NH), 256, 0, stream>>>(
          qb, HD, (long)S * HD, kb, HD, 0, scp, S, (long)S * S, HD, 0.0625f, 0, 512, 1);
    softmax_kernel<<<dim3(S, NH), 256, 0, stream>>>(scp, P, full ? 0 : 1);
    gemm_nt<u16, 0, 64><<<dim3(2, 8, NH), 256, 0, stream>>>(
        P, S, (long)S * S, vt, S, 0, o, NH * HD, HD, S, 1.0f, full ? 2 : 1, -1, 1);
    gemm_nt<float, 0, 64><<<dim3(5, 8, 2), 256, 0, stream>>>(
        o, NH * HD, 0, woT, NH * HD, 0, t1, H, (long)S * H, NH * HD, 1.0f, 3, -1, 2);
    fused_add_norm<<<S, 256, 0, stream>>>(h, t1, 2, ln2 + l * H, ln3 + l * H, x);

    gemm_nt<u16, 1, 64><<<dim3(32, 8, 1), 256, 0, stream>>>(
        x, H, 0, wguT, H, 0, mg, I, 0, H, 1.0f, 0, -1, 1);
    gemm_nt<float, 0, 64><<<dim3(5, 8, 4), 256, 0, stream>>>(
        mg, I, 0, wdT, I, 0, t1, H, (long)S * H, I, 1.0f, 3, -1, 4);
    fused_add_norm<<<S, 256, 0, stream>>>(h, t1, 4, ln4 + l * H,
                                          (l == 17) ? nw : ln1 + (l + 1) * H,
                                          (l == 17) ? hn : x);
  }

  // logits = hn @ embT^T — BK=32 variant (conflict-free swizzle)
  gemm_nt<float, 0, 32><<<dim3(V / 128, 8, 1), 256, 0, stream>>>(
      hn, H, 0, embT, H, 0, out, V, 0, H, 1.0f, 0, -1, 1);
}